// Round 1
// 1461.443 us; speedup vs baseline: 1.4509x; 1.4509x over previous
//
#include <hip/hip_runtime.h>
#include <stdint.h>

typedef uint16_t u16;
typedef __attribute__((ext_vector_type(8))) short s16x8;
typedef __attribute__((ext_vector_type(4))) float f32x4;

typedef const __attribute__((address_space(1))) void* gptr_t;
typedef __attribute__((address_space(3))) void* lptr_t;

__device__ __forceinline__ float bf2f(u16 u) { return __uint_as_float(((unsigned)u) << 16); }
__device__ __forceinline__ u16 f2bf(float f) {
    unsigned u = __float_as_uint(f);
    u += 0x7fffu + ((u >> 16) & 1u);   // RNE (finite values only in this net)
    return (u16)(u >> 16);
}
__device__ __forceinline__ void gld_lds16(const void* g, void* l) {
    __builtin_amdgcn_global_load_lds((gptr_t)g, (lptr_t)l, 16, 0, 0);
}

// ---------------------------------------------------------------------------
// f32 -> bf16 conversion, 8 elems/thread, n % 2048 == 0
// ---------------------------------------------------------------------------
__global__ __launch_bounds__(256) void cvt_f32_bf16(const float* __restrict__ src,
                                                    u16* __restrict__ dst, long n)
{
    const long i = ((long)blockIdx.x * 256 + threadIdx.x) * 8;
    if (i >= n) return;
    float4 a = *(const float4*)(src + i);
    float4 b = *(const float4*)(src + i + 4);
    u16 o8[8] = { f2bf(a.x), f2bf(a.y), f2bf(a.z), f2bf(a.w),
                  f2bf(b.x), f2bf(b.y), f2bf(b.z), f2bf(b.w) };
    *(uint4*)(dst + i) = *(const uint4*)o8;
}

// ---------------------------------------------------------------------------
// GEMM:  C[M,N] = A[M,K] @ B[N,K]^T   (A,B bf16, K-contiguous)
// m97 structure: 128x128 tile, BK=32, 4 waves (2x2 of 64x64), 16x16x32 MFMA.
// ep=0: Cb[idx] = bf16(acc)        ep=1: Cf[idx] = acc + Rf[idx]   (f32)
// ---------------------------------------------------------------------------
__global__ __launch_bounds__(256) void gemm_bt(
        const u16* __restrict__ A, const u16* __restrict__ B,
        u16* __restrict__ Cb, float* __restrict__ Cf, const float* __restrict__ Rf,
        int M, int N, int K, int ep)
{
    __shared__ __align__(16) u16 As[128 * 32];
    __shared__ __align__(16) u16 Bs[128 * 32];

    const int tid  = threadIdx.x;
    const int wave = tid >> 6, lane = tid & 63;
    const int quad = lane >> 4, l16 = lane & 15;
    const long m0 = (long)blockIdx.y * 128, n0 = (long)blockIdx.x * 128;
    const int wm = (wave >> 1) * 64, wn = (wave & 1) * 64;

    f32x4 acc[4][4] = {};

    // staging: 512 chunks of 16B per tile; chunk c -> row c>>2, cols (c&3)*8..+8
    const int c0 = tid, c1 = tid + 256;
    const u16* Ag = A + m0 * (long)K;
    const u16* Bg = B + n0 * (long)K;
    const long a0 = (long)(c0 >> 2) * K + (c0 & 3) * 8;
    const long a1 = (long)(c1 >> 2) * K + (c1 & 3) * 8;
    const int lb0 = (wave * 64) * 8;          // wave-uniform LDS base, elements
    const int lb1 = (256 + wave * 64) * 8;

    for (int k0 = 0; k0 < K; k0 += 32) {
        __syncthreads();                       // prev iter's LDS reads done
        gld_lds16(Ag + a0 + k0, &As[lb0]);
        gld_lds16(Ag + a1 + k0, &As[lb1]);
        gld_lds16(Bg + a0 + k0, &Bs[lb0]);
        gld_lds16(Bg + a1 + k0, &Bs[lb1]);
        __syncthreads();                       // drains vmcnt -> staging visible

        s16x8 af[4], bfr[4];
#pragma unroll
        for (int t = 0; t < 4; t++) {
            af[t]  = *(const s16x8*)&As[(wm + t * 16 + l16) * 32 + quad * 8];
            bfr[t] = *(const s16x8*)&Bs[(wn + t * 16 + l16) * 32 + quad * 8];
        }
#pragma unroll
        for (int mt = 0; mt < 4; mt++)
#pragma unroll
            for (int nt = 0; nt < 4; nt++)
                acc[mt][nt] = __builtin_amdgcn_mfma_f32_16x16x32_bf16(
                    af[mt], bfr[nt], acc[mt][nt], 0, 0, 0);
    }

    // epilogue: C/D layout col=lane&15, row=quad*4+reg
#pragma unroll
    for (int mt = 0; mt < 4; mt++)
#pragma unroll
        for (int nt = 0; nt < 4; nt++) {
            const long col = n0 + wn + nt * 16 + l16;
#pragma unroll
            for (int r = 0; r < 4; r++) {
                const long row = m0 + wm + mt * 16 + quad * 4 + r;
                const long idx = row * N + col;
                const float v = acc[mt][nt][r];
                if (ep == 0) Cb[idx] = f2bf(v);
                else         Cf[idx] = v + Rf[idx];
            }
        }
}

// ---------------------------------------------------------------------------
// Flash attention, Br=64 (16 q-rows/wave), Bc=64, head_dim=128, S=2048.
// q/k/v (bf16) layout: [B,S,NH,HD] (row stride 2048). bias/mask f32.
// LDS tiles XOR-swizzled for bank-conflict-free access (T2 / Guideline 4):
//   Ks: [k][d ^ ((k&7)<<3)]        staged via pre-swizzled global src (m173)
//   Vt: [d][k ^ (((d&7)^((d>>3)&7))<<3)]   (transposed, stride 64, no pad)
//   Ps: [row][col ^ ((row&7)<<3)]          (stride 64)
// Total LDS 40960 B = 160KB/4 -> 4 blocks/CU.
// ---------------------------------------------------------------------------
__global__ __launch_bounds__(256) void flash_attn(
        const u16* __restrict__ Q, const u16* __restrict__ Kp,
        const u16* __restrict__ V, const float* __restrict__ bias,
        const float* __restrict__ mask, u16* __restrict__ O)
{
    const int tid  = threadIdx.x;
    const int wave = tid >> 6, lane = tid & 63;
    const int quad = lane >> 4, l16 = lane & 15;
    const int q0 = blockIdx.x * 64, h = blockIdx.y, b = blockIdx.z;

    __shared__ __align__(16) u16 Ks[64 * 128];      // [k][d] row-major, swizzled
    __shared__ __align__(16) u16 Vt[128 * 64];      // [d][k] transposed, swizzled
    __shared__ __align__(16) u16 Ps[4][16 * 64];    // per-wave P, swizzled

    const long base = (long)b * 2048 * 2048 + (long)h * 128;  // + s*2048 + d

    // Q fragments (A layout: m=l16, k = kk*32+quad*8+j)
    s16x8 qf[4];
    {
        const u16* qp = Q + base + (long)(q0 + wave * 16 + l16) * 2048;
#pragma unroll
        for (int kk = 0; kk < 4; kk++)
            qf[kk] = *(const s16x8*)(qp + kk * 32 + quad * 8);
    }

    f32x4 oacc[8] = {};
    float m_i[4] = { -1e30f, -1e30f, -1e30f, -1e30f };
    float l_i[4] = { 0.f, 0.f, 0.f, 0.f };
    const float scale = 0.08838834764831845f;  // 1/sqrt(128)
    const int kswz = (l16 & 7) << 3;           // Ks/Ps read-side swizzle

    for (int k0 = 0; k0 < 2048; k0 += 64) {
        __syncthreads();
        // stage K via global_load_lds: LDS dest linear, global src column
        // pre-swizzled so LDS holds K[row][col ^ ((row&7)<<3)]
#pragma unroll
        for (int it = 0; it < 4; it++) {
            const int c = it * 256 + tid;
            const int row = c >> 4, col8 = (c & 15) * 8;
            const int src = col8 ^ ((row & 7) << 3);
            gld_lds16(Kp + base + (long)(k0 + row) * 2048 + src,
                      &Ks[(it * 256 + wave * 64) * 8]);
        }
        // stage V transposed (16B loads + swizzled scalar LDS writes)
#pragma unroll
        for (int it = 0; it < 4; it++) {
            const int c = it * 256 + tid;
            const int row = c >> 4, col8 = (c & 15) * 8;
            uint4 raw = *(const uint4*)(V + base + (long)(k0 + row) * 2048 + col8);
            const u16* e = (const u16*)&raw;
#pragma unroll
            for (int j = 0; j < 8; j++) {
                const int d = col8 + j;
                const int swz = ((d & 7) ^ ((d >> 3) & 7)) << 3;
                Vt[d * 64 + (row ^ swz)] = e[j];
            }
        }
        __syncthreads();

        // S = Q @ K^T  (per wave: 16 q-rows x 64 k-cols)
        float sv[4][4];
#pragma unroll
        for (int nt = 0; nt < 4; nt++) {
            f32x4 sa = { 0.f, 0.f, 0.f, 0.f };
#pragma unroll
            for (int kk = 0; kk < 4; kk++) {
                // krow&7 == l16&7 (nt*16 has no low bits)
                s16x8 kf = *(const s16x8*)&Ks[(nt * 16 + l16) * 128
                                              + ((kk * 32 + quad * 8) ^ kswz)];
                sa = __builtin_amdgcn_mfma_f32_16x16x32_bf16(qf[kk], kf, sa, 0, 0, 0);
            }
            const int kcol = k0 + nt * 16 + l16;
#pragma unroll
            for (int r = 0; r < 4; r++) {
                const int qrow = q0 + wave * 16 + quad * 4 + r;
                float val = sa[r] * scale;
                val += bias[((long)h * 2048 + qrow) * 2048 + kcol];
                val += mask[(long)qrow * 2048 + kcol];
                sv[nt][r] = val;
            }
        }

        // online softmax per q-row (rows quad*4+r; 16 k-lanes per quad)
        float alpha[4];
#pragma unroll
        for (int r = 0; r < 4; r++) {
            float mx = fmaxf(fmaxf(sv[0][r], sv[1][r]), fmaxf(sv[2][r], sv[3][r]));
#pragma unroll
            for (int off = 1; off < 16; off <<= 1) mx = fmaxf(mx, __shfl_xor(mx, off));
            const float mnew = fmaxf(m_i[r], mx);
            alpha[r] = __expf(m_i[r] - mnew);
            m_i[r] = mnew;
            float rs = 0.f;
#pragma unroll
            for (int nt = 0; nt < 4; nt++) {
                const float pv = __expf(sv[nt][r] - mnew);
                sv[nt][r] = pv;
                rs += pv;
            }
#pragma unroll
            for (int off = 1; off < 16; off <<= 1) rs += __shfl_xor(rs, off);
            l_i[r] = l_i[r] * alpha[r] + rs;
        }

        // P: C-layout -> A-layout via per-wave LDS round-trip (swizzled)
#pragma unroll
        for (int nt = 0; nt < 4; nt++)
#pragma unroll
            for (int r = 0; r < 4; r++) {
                const int prow = quad * 4 + r;
                Ps[wave][prow * 64 + ((nt * 16 + l16) ^ ((prow & 7) << 3))]
                    = f2bf(sv[nt][r]);
            }

        // rescale O accumulator
#pragma unroll
        for (int dt = 0; dt < 8; dt++)
#pragma unroll
            for (int r = 0; r < 4; r++)
                oacc[dt][r] *= alpha[r];

        // O += P @ V   (n = d-tiles, k = k-cols; Vt gives k-contiguous B-frags)
#pragma unroll
        for (int kk2 = 0; kk2 < 2; kk2++) {
            // Ps row == l16, so read swizzle == kswz
            s16x8 pf = *(const s16x8*)&Ps[wave][l16 * 64
                                               + ((kk2 * 32 + quad * 8) ^ kswz)];
#pragma unroll
            for (int dt = 0; dt < 8; dt++) {
                const int d = dt * 16 + l16;
                const int vswz = ((d & 7) ^ ((d >> 3) & 7)) << 3;
                s16x8 vf = *(const s16x8*)&Vt[d * 64
                                              + ((kk2 * 32 + quad * 8) ^ vswz)];
                oacc[dt] = __builtin_amdgcn_mfma_f32_16x16x32_bf16(pf, vf, oacc[dt], 0, 0, 0);
            }
        }
    }

    // epilogue: O / l
#pragma unroll
    for (int dt = 0; dt < 8; dt++)
#pragma unroll
        for (int r = 0; r < 4; r++) {
            const int qrow = q0 + wave * 16 + quad * 4 + r;
            O[base + (long)qrow * 2048 + dt * 16 + l16] = f2bf(oacc[dt][r] / l_i[r]);
        }
}

// ---------------------------------------------------------------------------
// RMSNorm: f32 in (row of 2048), f32 weight, bf16 out. One block per row.
// ---------------------------------------------------------------------------
__global__ __launch_bounds__(256) void rmsnorm_f32(
        const float* __restrict__ x, const float* __restrict__ w,
        u16* __restrict__ out)
{
    const int row = blockIdx.x, tid = threadIdx.x;
    const float* xr = x + (long)row * 2048;
    float4 f0 = *(const float4*)(xr + tid * 8);
    float4 f1 = *(const float4*)(xr + tid * 8 + 4);
    float v[8] = { f0.x, f0.y, f0.z, f0.w, f1.x, f1.y, f1.z, f1.w };
    float ss = 0.f;
#pragma unroll
    for (int j = 0; j < 8; j++) ss += v[j] * v[j];
#pragma unroll
    for (int off = 32; off > 0; off >>= 1) ss += __shfl_xor(ss, off);
    __shared__ float red[4];
    if ((tid & 63) == 0) red[tid >> 6] = ss;
    __syncthreads();
    const float tot = red[0] + red[1] + red[2] + red[3];
    const float sc = rsqrtf(tot * (1.0f / 2048.0f) + 1e-5f);
    float4 w0 = *(const float4*)(w + tid * 8);
    float4 w1v = *(const float4*)(w + tid * 8 + 4);
    const float wv[8] = { w0.x, w0.y, w0.z, w0.w, w1v.x, w1v.y, w1v.z, w1v.w };
    u16 o8[8];
#pragma unroll
    for (int j = 0; j < 8; j++) o8[j] = f2bf(v[j] * sc * wv[j]);
    *(uint4*)(out + (long)row * 2048 + tid * 8) = *(const uint4*)o8;
}

// ---------------------------------------------------------------------------
// g = silu(a) * b  (bf16 in/out; may run in-place on a)
// ---------------------------------------------------------------------------
__global__ __launch_bounds__(256) void silu_mul(
        const u16* __restrict__ a, const u16* __restrict__ b, u16* __restrict__ g)
{
    const long i = ((long)blockIdx.x * 256 + threadIdx.x) * 8;
    uint4 ra = *(const uint4*)(a + i);
    uint4 rb = *(const uint4*)(b + i);
    const u16* ea = (const u16*)&ra;
    const u16* eb = (const u16*)&rb;
    u16 o8[8];
#pragma unroll
    for (int j = 0; j < 8; j++) {
        const float fa = bf2f(ea[j]);
        const float fb = bf2f(eb[j]);
        const float s = fa / (1.f + __expf(-fa));
        o8[j] = f2bf(s * fb);
    }
    *(uint4*)(g + i) = *(const uint4*)o8;
}

// ---------------------------------------------------------------------------
extern "C" void kernel_launch(void* const* d_in, const int* in_sizes, int n_in,
                              void* d_out, int out_size, void* d_ws, size_t ws_size,
                              hipStream_t stream)
{
    const float* x    = (const float*)d_in[0];
    const float* mask = (const float*)d_in[1];
    const float* bias = (const float*)d_in[2];
    const float* wq   = (const float*)d_in[3];
    const float* wk   = (const float*)d_in[4];
    const float* wv   = (const float*)d_in[5];
    const float* wo   = (const float*)d_in[6];
    const float* w1   = (const float*)d_in[7];
    const float* w2   = (const float*)d_in[8];
    const float* w3   = (const float*)d_in[9];
    const float* anw  = (const float*)d_in[10];
    const float* fnw  = (const float*)d_in[11];
    float* out = (float*)d_out;       // also doubles as h1 (f32 residual buffer)

    const long SZA = 2048L * 2048;    // attention weight elems
    const long SZF = 5632L * 2048;    // FFN weight elems

    char* p = (char*)d_ws;
    u16* wqb = (u16*)p;  u16* wkb = wqb + SZA;  u16* wvb = wkb + SZA;
    u16* wob = wvb + SZA;
    u16* w1b = wob + SZA;  u16* w2b = w1b + SZF;  u16* w3b = w2b + SZF;
    p += (4 * SZA + 3 * SZF) * 2;
    const size_t SZ = (size_t)4096 * 2048 * 2;           // 16 MiB bf16 activation
    u16* h_buf = (u16*)p;  p += SZ;                      // h, later attn_out
    u16* q_buf = (u16*)p;  p += SZ;                      // q, later f
    u16* k_buf = (u16*)p;  p += SZ;
    u16* v_buf = (u16*)p;  p += SZ;
    u16* s1    = (u16*)p;  p += (size_t)4096 * 5632 * 2; // later g (in-place)
    u16* s3    = (u16*)p;  p += (size_t)4096 * 5632 * 2;
    // total ws used ~262 MB

    // weights f32 -> bf16
    cvt_f32_bf16<<<2048, 256, 0, stream>>>(wq, wqb, SZA);
    cvt_f32_bf16<<<2048, 256, 0, stream>>>(wk, wkb, SZA);
    cvt_f32_bf16<<<2048, 256, 0, stream>>>(wv, wvb, SZA);
    cvt_f32_bf16<<<2048, 256, 0, stream>>>(wo, wob, SZA);
    cvt_f32_bf16<<<5632, 256, 0, stream>>>(w1, w1b, SZF);
    cvt_f32_bf16<<<5632, 256, 0, stream>>>(w2, w2b, SZF);
    cvt_f32_bf16<<<5632, 256, 0, stream>>>(w3, w3b, SZF);

    rmsnorm_f32<<<4096, 256, 0, stream>>>(x, anw, h_buf);
    gemm_bt<<<dim3(16, 32), 256, 0, stream>>>(h_buf, wqb, q_buf, nullptr, nullptr, 4096, 2048, 2048, 0);
    gemm_bt<<<dim3(16, 32), 256, 0, stream>>>(h_buf, wkb, k_buf, nullptr, nullptr, 4096, 2048, 2048, 0);
    gemm_bt<<<dim3(16, 32), 256, 0, stream>>>(h_buf, wvb, v_buf, nullptr, nullptr, 4096, 2048, 2048, 0);
    flash_attn<<<dim3(32, 16, 2), 256, 0, stream>>>(q_buf, k_buf, v_buf, bias, mask, h_buf);
    // h1 = x + attn_out @ wo^T   (f32, stored in d_out)
    gemm_bt<<<dim3(16, 32), 256, 0, stream>>>(h_buf, wob, nullptr, out, x, 4096, 2048, 2048, 1);
    rmsnorm_f32<<<4096, 256, 0, stream>>>(out, fnw, q_buf);
    gemm_bt<<<dim3(44, 32), 256, 0, stream>>>(q_buf, w1b, s1, nullptr, nullptr, 4096, 5632, 2048, 0);
    gemm_bt<<<dim3(44, 32), 256, 0, stream>>>(q_buf, w3b, s3, nullptr, nullptr, 4096, 5632, 2048, 0);
    silu_mul<<<11264, 256, 0, stream>>>(s1, s3, s1);
    // out = h1 + g @ w2^T   (reads h1 from d_out, writes final out in place)
    gemm_bt<<<dim3(16, 32), 256, 0, stream>>>(s1, w2b, nullptr, out, out, 4096, 2048, 5632, 1);
}